// Round 2
// baseline (83.058 us; speedup 1.0000x reference)
//
#include <hip/hip_runtime.h>
#include <math.h>

// Kendall's Tau loss, n=8192 fp32 — single fused kernel.
// disc = #{(i,j): (p_i<p_j) != (t_i<t_j)} over ordered pairs (i != j; i==j
// contributes 0). sum S = n(n-1) - 2*disc; loss = 2*disc/(n(n-1)). Integer-exact.
//
// Structure: 1024 blocks (4/CU, 4 waves/SIMD), IPT=8 register blocking,
// wave-uniform ds_read_b128 j-tile broadcast (2 j's per read), fully static
// inner loop (tails neutralized by +INF padding: (inf<x)==(inf<y)==false -> 0).
// Finalization fused via device-scope atomic + ticket; the last block computes
// the loss and self-resets the module-scope accumulators (graph-replay-safe).
// d_ws is unused.

constexpr int BLK = 256;       // threads per block
constexpr int IPT = 8;         // i's per thread (independent acc chains)
constexpr int TI  = BLK * IPT; // 2048 i's per block
constexpr int TJ  = 32;        // j's per block tile (256 B LDS)

__device__ int g_disc   = 0;   // zero at module load; self-reset each launch
__device__ int g_ticket = 0;

__global__ __launch_bounds__(BLK) void ktau_fused(
    const float* __restrict__ p, const float* __restrict__ t,
    float* __restrict__ out, int n, int nblocks) {
  __shared__ __align__(16) float2 jv[TJ];
  const int tid = threadIdx.x;
  const int i0  = blockIdx.x * TI;
  const int j0  = blockIdx.y * TJ;

  if (tid < TJ) {
    int j = j0 + tid;
    jv[tid] = (j < n) ? make_float2(p[j], t[j])
                      : make_float2(INFINITY, INFINITY);  // pad: contributes 0
  }

  float pi[IPT], ti[IPT];
#pragma unroll
  for (int m = 0; m < IPT; ++m) {
    int i  = i0 + tid + m * BLK;
    int ic = i < n ? i : 0;           // clamped load, then neutralize via INF
    float pv = p[ic], tv = t[ic];
    pi[m] = (i < n) ? pv : INFINITY;
    ti[m] = (i < n) ? tv : INFINITY;
  }
  __syncthreads();

  int acc[IPT] = {};
  const float4* jv4 = reinterpret_cast<const float4*>(jv);
#pragma unroll
  for (int k2 = 0; k2 < TJ / 2; ++k2) {
    float4 w = jv4[k2];   // wave-uniform broadcast, ds_read_b128: j and j+1
#pragma unroll
    for (int m = 0; m < IPT; ++m) {
      acc[m] += (int)((pi[m] < w.x) != (ti[m] < w.y));
      acc[m] += (int)((pi[m] < w.z) != (ti[m] < w.w));
    }
  }

  int sum = 0;
#pragma unroll
  for (int m = 0; m < IPT; ++m) sum += acc[m];

  // 64-lane wave reduce, then cross-wave via LDS
  for (int off = 32; off > 0; off >>= 1)
    sum += __shfl_down(sum, off, 64);
  __shared__ int wsum[BLK / 64];
  if ((tid & 63) == 0) wsum[tid >> 6] = sum;
  __syncthreads();

  if (tid == 0) {
    int s = 0;
#pragma unroll
    for (int w = 0; w < BLK / 64; ++w) s += wsum[w];

    atomicAdd(&g_disc, s);            // device-scope, cross-XCD coherent
    __threadfence();
    int old = atomicAdd(&g_ticket, 1);
    if (old == nblocks - 1) {
      // Last block: all partials are in (each add happens-before its ticket).
      int disc = atomicAdd(&g_disc, 0);  // RMW read: coherent, never stale
      double nn = (double)n * (double)(n - 1);
      double S  = nn - 2.0 * (double)disc;  // diagonal contributes 0
      out[0] = (float)(1.0 - S / nn);
      // Self-reset for the next graph replay (no other block touches these
      // after its ticket increment; next launch is stream-ordered after us).
      atomicExch(&g_disc, 0);
      atomicExch(&g_ticket, 0);
    }
  }
}

extern "C" void kernel_launch(void* const* d_in, const int* in_sizes, int n_in,
                              void* d_out, int out_size, void* d_ws, size_t ws_size,
                              hipStream_t stream) {
  const float* p = (const float*)d_in[0];
  const float* t = (const float*)d_in[1];
  float* out = (float*)d_out;
  const int n = in_sizes[0];

  const int gx = (n + TI - 1) / TI;   // 4
  const int gy = (n + TJ - 1) / TJ;   // 256
  dim3 grid(gx, gy);

  ktau_fused<<<grid, BLK, 0, stream>>>(p, t, out, n, gx * gy);
}

// Round 3
// 65.096 us; speedup vs baseline: 1.2759x; 1.2759x over previous
//
#include <hip/hip_runtime.h>
#include <math.h>

// Kendall's Tau loss, n=8192 fp32 — single fused kernel, low-contention tail.
// disc = #{(i,j): (p_i<p_j) != (t_i<t_j)} over ordered pairs (i != j; i==j
// contributes 0). sum S = n(n-1) - 2*disc; loss = 2*disc/(n(n-1)). Integer-exact.
//
// Structure: 256 blocks x 1024 threads (1 block/CU, 16 waves/CU). Block y
// covers ALL i (8192 = 1024 thr * IPT=8 register chains) x a TJ=32 j-tile
// broadcast from LDS via wave-uniform ds_read_b128 (2 j's per read). Fully
// static inner loop; tails neutralized by +INF padding ((inf<x)==(inf<y) -> 0).
//
// Cross-block finalization: ONE packed 64-bit atomicAdd per block
// (disc<<20 | 1). Returned 'old' carries both arrival count (low 20b) and
// running disc (high 44b) -> no ticket, no fence, no re-read. 256 same-line
// RMWs ~= 1.8 us tail (vs 35 us for 2048 in the previous version). Last
// arriver writes the loss and atomicExch-resets (graph-replay-safe).
// d_ws unused.

constexpr int BLK = 1024;      // threads per block
constexpr int IPT = 8;         // i's per thread (independent acc chains)
constexpr int TI  = BLK * IPT; // 8192 i's per block
constexpr int TJ  = 32;        // j's per block tile (256 B LDS)

__device__ unsigned long long g_packed = 0;  // [disc:44 | count:20]

__global__ __launch_bounds__(BLK) void ktau_fused(
    const float* __restrict__ p, const float* __restrict__ t,
    float* __restrict__ out, int n, int nblocks) {
  __shared__ __align__(16) float2 jv[TJ];
  const int tid = threadIdx.x;
  const int i0  = blockIdx.x * TI;
  const int j0  = blockIdx.y * TJ;

  if (tid < TJ) {
    int j = j0 + tid;
    jv[tid] = (j < n) ? make_float2(p[j], t[j])
                      : make_float2(INFINITY, INFINITY);  // pad: contributes 0
  }

  float pi[IPT], ti[IPT];
#pragma unroll
  for (int m = 0; m < IPT; ++m) {
    int i  = i0 + tid + m * BLK;
    int ic = i < n ? i : 0;           // clamped load, then neutralize via INF
    float pv = p[ic], tv = t[ic];
    pi[m] = (i < n) ? pv : INFINITY;
    ti[m] = (i < n) ? tv : INFINITY;
  }
  __syncthreads();

  int acc[IPT] = {};
  const float4* jv4 = reinterpret_cast<const float4*>(jv);
#pragma unroll
  for (int k2 = 0; k2 < TJ / 2; ++k2) {
    float4 w = jv4[k2];   // wave-uniform broadcast, ds_read_b128: j and j+1
#pragma unroll
    for (int m = 0; m < IPT; ++m) {
      acc[m] += (int)((pi[m] < w.x) != (ti[m] < w.y));
      acc[m] += (int)((pi[m] < w.z) != (ti[m] < w.w));
    }
  }

  int sum = 0;
#pragma unroll
  for (int m = 0; m < IPT; ++m) sum += acc[m];

  // 64-lane wave reduce, then cross-wave via LDS
  for (int off = 32; off > 0; off >>= 1)
    sum += __shfl_down(sum, off, 64);
  __shared__ int wsum[BLK / 64];
  if ((tid & 63) == 0) wsum[tid >> 6] = sum;
  __syncthreads();

  if (tid == 0) {
    long long s = 0;
#pragma unroll
    for (int w = 0; w < BLK / 64; ++w) s += wsum[w];

    // One device-scope RMW per block; value carries count AND partial sum.
    unsigned long long pack = ((unsigned long long)s << 20) | 1ull;
    unsigned long long old  = atomicAdd(&g_packed, pack);
    if ((old & 0xFFFFFull) == (unsigned long long)(nblocks - 1)) {
      // Last arriver: all adds complete (count was nblocks-1 before ours).
      long long disc = (long long)((old >> 20)) + s;
      double nn = (double)n * (double)(n - 1);
      double S  = nn - 2.0 * (double)disc;  // diagonal contributes 0
      out[0] = (float)(1.0 - S / nn);
      atomicExch(&g_packed, 0ull);          // reset for next graph replay
    }
  }
}

extern "C" void kernel_launch(void* const* d_in, const int* in_sizes, int n_in,
                              void* d_out, int out_size, void* d_ws, size_t ws_size,
                              hipStream_t stream) {
  const float* p = (const float*)d_in[0];
  const float* t = (const float*)d_in[1];
  float* out = (float*)d_out;
  const int n = in_sizes[0];

  const int gx = (n + TI - 1) / TI;   // 1
  const int gy = (n + TJ - 1) / TJ;   // 256
  dim3 grid(gx, gy);

  ktau_fused<<<grid, BLK, 0, stream>>>(p, t, out, n, gx * gy);
}